// Round 10
// baseline (345.848 us; speedup 1.0000x reference)
//
#include <hip/hip_runtime.h>
#include <cstdint>

#define CAP_ 1088
#define EPS_ 1e-5f

using bf8   = __attribute__((ext_vector_type(8))) short;
using f32x4 = __attribute__((ext_vector_type(4))) float;

__device__ __forceinline__ unsigned short f2bf(float f) {
  unsigned u = __float_as_uint(f);
  u += 0x7fffu + ((u >> 16) & 1);
  return (unsigned short)(u >> 16);
}
__device__ __forceinline__ float bf2f(unsigned short v) {
  return __uint_as_float((unsigned)v << 16);
}

typedef const __attribute__((address_space(1))) void* gp1;
typedef __attribute__((address_space(3))) void* lp3;
__device__ __forceinline__ void async16(const void* g, void* l) {
  __builtin_amdgcn_global_load_lds((gp1)g, (lp3)l, 16, 0, 0);
}

// ---------------------------------------------------------------------------
// All fp32->bf16 conversions in ONE kernel (segmented by blockIdx).
// ---------------------------------------------------------------------------
__global__ __launch_bounds__(256) void cvt_all(
    const float* __restrict__ x, const float* __restrict__ dx,
    const float* __restrict__ qkvw, const float* __restrict__ outw,
    const float* __restrict__ w1, const float* __restrict__ w2,
    unsigned short* __restrict__ x_bf, unsigned short* __restrict__ qkvw_bf,
    unsigned short* __restrict__ outw_bf, unsigned short* __restrict__ w1_bf,
    unsigned short* __restrict__ w2_bf)
{
  const int bid = blockIdx.x;
  const float* src; unsigned short* dst; int c;
  if      (bid < 4096) { src = x;    dst = x_bf;                      c = bid;        }
  else if (bid < 4352) { src = dx;   dst = x_bf + (size_t)8192 * 512; c = bid - 4096; }
  else if (bid < 5120) { src = qkvw; dst = qkvw_bf;                   c = bid - 4352; }
  else if (bid < 5376) { src = outw; dst = outw_bf;                   c = bid - 5120; }
  else if (bid < 6400) { src = w1;   dst = w1_bf;                     c = bid - 5376; }
  else                 { src = w2;   dst = w2_bf;                     c = bid - 6400; }
  const int i = c * 256 + threadIdx.x;
  float4 v = ((const float4*)src)[i];
  ushort4 o;
  o.x = f2bf(v.x); o.y = f2bf(v.y); o.z = f2bf(v.z); o.w = f2bf(v.w);
  ((ushort4*)dst)[i] = o;
}

// ---------------------------------------------------------------------------
// bf16 MFMA GEMM NT (128x128 tile, BK=64, 4 waves): QKV (mode 1) and
// MLP1 (mode 2, bf16 C + relu). Unchanged.
// ---------------------------------------------------------------------------
__global__ __launch_bounds__(256) void mfma_gemm(
    const unsigned short* __restrict__ A, const unsigned short* __restrict__ Bw,
    const float* __restrict__ bias,
    unsigned short* __restrict__ Cb,
    unsigned short* __restrict__ kb, unsigned short* __restrict__ vt,
    int M, int N, int K, int mode, int relu)
{
  __shared__ unsigned short Als[128 * 64];
  __shared__ unsigned short Bls[128 * 64];
  const int tid  = threadIdx.x;
  const int lane = tid & 63, w = tid >> 6;
  const int bm = blockIdx.x * 128, bn = blockIdx.y * 128;
  const int wm = (w >> 1) * 64, wn = (w & 1) * 64;

  f32x4 acc[4][4] = {};

  const int so = tid * 16;
  for (int k0 = 0; k0 < K; k0 += 64) {
#pragma unroll
    for (int it = 0; it < 4; ++it) {
      int o   = it * 4096 + so;
      int row = o >> 7;
      int ch  = (o >> 4) & 7;
      int sch = ch ^ (row & 7);
      async16(A  + (size_t)(bm + row) * K + k0 + sch * 8, (char*)Als + o);
      async16(Bw + (size_t)(bn + row) * K + k0 + sch * 8, (char*)Bls + o);
    }
    __syncthreads();
#pragma unroll
    for (int ks = 0; ks < 2; ++ks) {
      bf8 af[4], bfr[4];
#pragma unroll
      for (int m = 0; m < 4; ++m) {
        int row = wm + m * 16 + (lane & 15);
        int ch  = ks * 4 + (lane >> 4);
        af[m] = *(const bf8*)((const char*)Als + row * 128 + ((ch ^ (row & 7)) * 16));
      }
#pragma unroll
      for (int n = 0; n < 4; ++n) {
        int row = wn + n * 16 + (lane & 15);
        int ch  = ks * 4 + (lane >> 4);
        bfr[n] = *(const bf8*)((const char*)Bls + row * 128 + ((ch ^ (row & 7)) * 16));
      }
#pragma unroll
      for (int m = 0; m < 4; ++m)
#pragma unroll
        for (int n = 0; n < 4; ++n)
          acc[m][n] = __builtin_amdgcn_mfma_f32_16x16x32_bf16(af[m], bfr[n], acc[m][n], 0, 0, 0);
    }
    __syncthreads();
  }

#pragma unroll
  for (int m = 0; m < 4; ++m) {
#pragma unroll
    for (int n = 0; n < 4; ++n) {
      int col  = bn + wn + n * 16 + (lane & 15);
      int row0 = bm + wm + m * 16 + ((lane >> 4) << 2);
      float bcol = bias[col];
      if (mode == 1) {
        if (col < 512) {
#pragma unroll
          for (int r = 0; r < 4; ++r)
            Cb[((size_t)(row0 + r) << 9) + col] = f2bf((acc[m][n][r] + bcol) * 0.125f);
        } else if (col < 1024) {
#pragma unroll
          for (int r = 0; r < 4; ++r) {
            int row = row0 + r; int bb, pos;
            if (row < 8192) { bb = row >> 10; pos = row & 1023; }
            else { int r2 = row - 8192; bb = r2 & 7; pos = 1024 + (r2 >> 3); }
            kb[(((size_t)(bb * CAP_ + pos)) << 9) + (col - 512)] = f2bf(acc[m][n][r] + bcol);
          }
        } else {
          int c = col - 1024; int hh = c >> 6, d = c & 63;
          if (row0 < 8192) {
            int bb = row0 >> 10, pos = row0 & 1023;
            ushort4 pk;
            pk.x = f2bf(acc[m][n][0] + bcol); pk.y = f2bf(acc[m][n][1] + bcol);
            pk.z = f2bf(acc[m][n][2] + bcol); pk.w = f2bf(acc[m][n][3] + bcol);
            *(ushort4*)(vt + ((size_t)((bb * 8 + hh) * 64 + d)) * CAP_ + pos) = pk;
          } else {
#pragma unroll
            for (int r = 0; r < 4; ++r) {
              int r2 = row0 + r - 8192; int bb = r2 & 7, pos = 1024 + (r2 >> 3);
              vt[((size_t)((bb * 8 + hh) * 64 + d)) * CAP_ + pos] = f2bf(acc[m][n][r] + bcol);
            }
          }
        }
      } else {
#pragma unroll
        for (int r = 0; r < 4; ++r) {
          float v = acc[m][n][r] + bcol;
          if (relu) v = fmaxf(v, 0.f);
          Cb[(size_t)(row0 + r) * N + col] = f2bf(v);
        }
      }
    }
  }
}

// ---------------------------------------------------------------------------
// Full-row fused GEMM + residual + LayerNorm.
// 512 thr = 8 waves; block = 32 rows x 512 cols; wave wc computes cols
// [wc*64, wc*64+64). B staged BLOCK-WIDE (high MLP: 4 async16/thread = 32KB
// per BK=32 tile), double-buffered (2x32KB = 64KB -> 2 blocks/CU), with
// counted s_waitcnt vmcnt(6) + RAW s_barrier per tile (m201 pattern):
// tile t+1's 6 loads stay in flight across the barrier (no vmcnt-0 drain).
// A frags prefetched 1-deep in static even/odd registers.
// LDS layout per buffer: 2 B-rows per 128B line, slot s ^= line&7 (verified
// numerically in rounds 8/9). mode 0: bf16 out; mode 1: fp32 routed d_out.
// ---------------------------------------------------------------------------
__global__ __launch_bounds__(512) void gemm_fullrow_ln(
    const unsigned short* __restrict__ A,     // [8704][K]
    const unsigned short* __restrict__ Bw,    // [512][K]
    const float* __restrict__ bias,           // [512]
    const unsigned short* __restrict__ resb,  // [8704][512] bf16
    const float* __restrict__ lnw, const float* __restrict__ lnb,
    unsigned short* __restrict__ outb, float* __restrict__ outf,
    int K, int mode)
{
  __shared__ unsigned short Bls[2][16384];    // 2 x 32 KB
  const int tid = threadIdx.x, lane = tid & 63, wc = tid >> 6;
  const int l4 = lane >> 4, l15 = lane & 15;
  const int bm = blockIdx.x * 32;
  const int NT = K >> 5;                      // BK=32, NT even (16 or 64)

  f32x4 acc[2][4] = {};
  bf8 a0[2], a1[2];

  // Stage tile t (BK=32: 512 B-rows x 64B) into buffer buf, block-wide.
#define STAGE(t, buf)                                                        \
  {                                                                          \
    const int k0_ = (t) * 32;                                                \
    char* base_ = (char*)&Bls[(buf)][0];                                     \
    _Pragma("unroll")                                                        \
    for (int i_ = 0; i_ < 4; ++i_) {                                         \
      int loff_ = i_ * 8192 + tid * 16;                                      \
      int line_ = loff_ >> 7;                                                \
      int su_   = ((loff_ >> 4) & 7) ^ (line_ & 7);                          \
      async16(Bw + (size_t)(line_ * 2 + (su_ >> 2)) * K                      \
                 + k0_ + (su_ & 3) * 8,                                      \
              base_ + loff_);                                                \
    }                                                                        \
  }

#define LOADA(t, dst)                                                        \
  {                                                                          \
    const int k0_ = (t) * 32;                                                \
    _Pragma("unroll")                                                        \
    for (int mf_ = 0; mf_ < 2; ++mf_)                                        \
      dst[mf_] = *(const bf8*)(A + (size_t)(bm + mf_ * 16 + l15) * K         \
                               + k0_ + l4 * 8);                              \
  }

#define COMPUTE(buf, a)                                                      \
  {                                                                          \
    const char* base_ = (const char*)&Bls[(buf)][0];                         \
    _Pragma("unroll")                                                        \
    for (int nf_ = 0; nf_ < 4; ++nf_) {                                      \
      int row_  = wc * 64 + nf_ * 16 + l15;                                  \
      int line_ = row_ >> 1;                                                 \
      int s_    = (((row_ & 1) << 2) + l4) ^ (line_ & 7);                    \
      bf8 bv_ = *(const bf8*)(base_ + line_ * 128 + (s_ << 4));              \
      _Pragma("unroll")                                                      \
      for (int mf_ = 0; mf_ < 2; ++mf_)                                      \
        acc[mf_][nf_] = __builtin_amdgcn_mfma_f32_16x16x32_bf16(             \
            a[mf_], bv_, acc[mf_][nf_], 0, 0, 0);                            \
    }                                                                        \
  }

  // Prologue: tile 0 staged + A(0); loop keeps tile t+1 in flight.
  STAGE(0, 0); LOADA(0, a0);
  for (int t = 0; t < NT; t += 2) {
    // even half: compute tile t from buf0/a0; prefetch t+1 -> buf1/a1
    if (t + 1 < NT) {
      LOADA(t + 1, a1);
      STAGE(t + 1, 1);
      asm volatile("s_waitcnt vmcnt(6)" ::: "memory");  // tile t complete
    } else {
      asm volatile("s_waitcnt vmcnt(0)" ::: "memory");
    }
    __builtin_amdgcn_s_barrier();             // publish tile t (no drain)
    __builtin_amdgcn_sched_barrier(0);
    COMPUTE(0, a0);
    if (t + 1 < NT) {
      // odd half: compute t+1 from buf1/a1; prefetch t+2 -> buf0/a0
      if (t + 2 < NT) {
        LOADA(t + 2, a0);
        STAGE(t + 2, 0);
        asm volatile("s_waitcnt vmcnt(6)" ::: "memory");
      } else {
        asm volatile("s_waitcnt vmcnt(0)" ::: "memory");
      }
      __builtin_amdgcn_s_barrier();
      __builtin_amdgcn_sched_barrier(0);
      COMPUTE(1, a1);
    }
  }
#undef STAGE
#undef LOADA
#undef COMPUTE

  // ---- epilogue: bias + residual, then LN over the full 512-col row ----
  float bc[4], lw[4], lb[4];
#pragma unroll
  for (int nf = 0; nf < 4; ++nf) {
    int col = wc * 64 + nf * 16 + l15;
    bc[nf] = bias[col]; lw[nf] = lnw[col]; lb[nf] = lnb[col];
  }
#pragma unroll
  for (int nf = 0; nf < 4; ++nf) {
    int col = wc * 64 + nf * 16 + l15;
#pragma unroll
    for (int mf = 0; mf < 2; ++mf)
#pragma unroll
      for (int r = 0; r < 4; ++r) {
        int rowg = bm + mf * 16 + l4 * 4 + r;
        acc[mf][nf][r] += bc[nf] + bf2f(resb[(size_t)rowg * 512 + col]);
      }
  }

  __syncthreads();                             // all waves done with Bls
  float* red = (float*)Bls;                    // [32 rows][8 waves][2]
#pragma unroll
  for (int mf = 0; mf < 2; ++mf)
#pragma unroll
    for (int r = 0; r < 4; ++r) {
      float s = 0.f, q = 0.f;
#pragma unroll
      for (int nf = 0; nf < 4; ++nf) { float v = acc[mf][nf][r]; s += v; q += v * v; }
#pragma unroll
      for (int off = 1; off < 16; off <<= 1) {
        s += __shfl_xor(s, off, 64); q += __shfl_xor(q, off, 64);
      }
      if (l15 == 0) {
        int rl = mf * 16 + l4 * 4 + r;
        red[rl * 16 + wc * 2]     = s;
        red[rl * 16 + wc * 2 + 1] = q;
      }
    }
  __syncthreads();

#pragma unroll
  for (int mf = 0; mf < 2; ++mf)
#pragma unroll
    for (int r = 0; r < 4; ++r) {
      int rl = mf * 16 + l4 * 4 + r;
      float S = 0.f, Q = 0.f;
#pragma unroll
      for (int wq = 0; wq < 8; ++wq) {
        S += red[rl * 16 + wq * 2];
        Q += red[rl * 16 + wq * 2 + 1];
      }
      float mu  = S * (1.f / 512.f);
      float var = Q * (1.f / 512.f) - mu * mu;
      float inv = rsqrtf(var + EPS_);
      int rowg = bm + rl;
      if (mode == 0) {
#pragma unroll
        for (int nf = 0; nf < 4; ++nf) {
          int col = wc * 64 + nf * 16 + l15;
          float y = (acc[mf][nf][r] - mu) * inv * lw[nf] + lb[nf];
          outb[(size_t)rowg * 512 + col] = f2bf(y);
        }
      } else {
        int b, s2;
        if (rowg < 8192) { b = rowg >> 10; s2 = rowg & 1023; }
        else { int r2 = rowg - 8192; b = r2 & 7; s2 = 1024 + (r2 >> 3); }
        size_t ob = ((size_t)(b * CAP_ + s2)) << 9;
#pragma unroll
        for (int nf = 0; nf < 4; ++nf) {
          int col = wc * 64 + nf * 16 + l15;
          outf[ob + col] = (acc[mf][nf][r] - mu) * inv * lw[nf] + lb[nf];
        }
      }
    }
}

// ---------------------------------------------------------------------------
// MFMA attention (unchanged). grid (17,64).
// ---------------------------------------------------------------------------
__global__ __launch_bounds__(256) void attn_mfma(
    const unsigned short* __restrict__ qb,   // [8704][512], pre-scaled 1/8
    const unsigned short* __restrict__ kcb,  // [8][1088][512]
    const unsigned short* __restrict__ vtb,  // [8][8][64][1088]
    unsigned short* __restrict__ ob)         // [8704][512]
{
  __shared__ unsigned short Kls[4096];
  __shared__ unsigned short Vls[4096];
  __shared__ unsigned short Pls[4096];
  const int st = blockIdx.x, bh = blockIdx.y;
  const int b = bh >> 3, h = bh & 7;
  const bool dec = (st == 16);
  const int tid = threadIdx.x, lane = tid & 63, w = tid >> 6;
  const int wq = w * 16;
  const int nT = dec ? 17 : st + 1;
  const int qi = wq + (lane & 15);
  const size_t g = dec ? (size_t)(8192 + qi * 8 + b)
                       : (size_t)((b << 10) + st * 64 + qi);

  const bf8 qf0 = *(const bf8*)(qb + (g << 9) + h * 64 +      ((lane >> 4) << 3));
  const bf8 qf1 = *(const bf8*)(qb + (g << 9) + h * 64 + 32 + ((lane >> 4) << 3));

  f32x4 oo[4] = {};
  float m_ = -1e30f, l_ = 0.f;

  const size_t kbase = (((size_t)b * CAP_) << 9) + h * 64;
  const size_t vbase = (size_t)((b * 8 + h) * 64) * CAP_;

  for (int t = 0; t < nT; ++t) {
    const int t0 = t * 64;
    __syncthreads();
#pragma unroll
    for (int it = 0; it < 2; ++it) {
      int o   = it * 4096 + tid * 16;
      int row = o >> 7;
      int sch = ((o >> 4) & 7) ^ (row & 7);
      async16(kcb + kbase + (((size_t)(t0 + row)) << 9) + sch * 8, (char*)Kls + o);
      async16(vtb + vbase + (size_t)row * CAP_ + t0 + sch * 8,     (char*)Vls + o);
    }
    __syncthreads();

    f32x4 sfr[4] = {};
#pragma unroll
    for (int ks = 0; ks < 2; ++ks) {
      int cb = ks * 4 + (lane >> 4);
      bf8 qv = ks ? qf1 : qf0;
#pragma unroll
      for (int f = 0; f < 4; ++f) {
        int row = f * 16 + (lane & 15);
        bf8 kf = *(const bf8*)((const char*)Kls + row * 128 + ((cb ^ (row & 7)) << 4));
        sfr[f] = __builtin_amdgcn_mfma_f32_16x16x32_bf16(kf, qv, sfr[f], 0, 0, 0);
      }
    }
    if (t == nT - 1) {
#pragma unroll
      for (int f = 0; f < 4; ++f)
#pragma unroll
        for (int r = 0; r < 4; ++r) {
          int tr = f * 16 + ((lane >> 4) << 2) + r;
          if (tr > qi) sfr[f][r] = -1e30f;
        }
    }

    float pmax = -1e30f;
#pragma unroll
    for (int f = 0; f < 4; ++f)
#pragma unroll
      for (int r = 0; r < 4; ++r) pmax = fmaxf(pmax, sfr[f][r]);
    pmax = fmaxf(pmax, __shfl_xor(pmax, 16, 64));
    pmax = fmaxf(pmax, __shfl_xor(pmax, 32, 64));
    float mn  = fmaxf(m_, pmax);
    float fsc = __expf(m_ - mn);
    float rs = 0.f;
#pragma unroll
    for (int f = 0; f < 4; ++f)
#pragma unroll
      for (int r = 0; r < 4; ++r) {
        float e = __expf(sfr[f][r] - mn);
        sfr[f][r] = e; rs += e;
      }
    rs += __shfl_xor(rs, 16, 64);
    rs += __shfl_xor(rs, 32, 64);
    l_ = l_ * fsc + rs; m_ = mn;
#pragma unroll
    for (int f = 0; f < 4; ++f) oo[f] *= fsc;

#pragma unroll
    for (int f = 0; f < 4; ++f) {
      ushort4 pk;
      pk.x = f2bf(sfr[f][0]); pk.y = f2bf(sfr[f][1]);
      pk.z = f2bf(sfr[f][2]); pk.w = f2bf(sfr[f][3]);
      int tb   = f * 32 + ((lane >> 4) << 3);
      int addr = qi * 128 + ((((tb >> 4)) ^ (qi & 7)) << 4) + (tb & 15);
      *(ushort4*)((char*)Pls + addr) = pk;
    }
    __syncthreads();

#pragma unroll
    for (int ks = 0; ks < 2; ++ks) {
      int cb = ks * 4 + (lane >> 4);
      bf8 pf = *(const bf8*)((const char*)Pls + qi * 128 + ((cb ^ (qi & 7)) << 4));
#pragma unroll
      for (int f = 0; f < 4; ++f) {
        int row = f * 16 + (lane & 15);
        bf8 vf = *(const bf8*)((const char*)Vls + row * 128 + ((cb ^ (row & 7)) << 4));
        oo[f] = __builtin_amdgcn_mfma_f32_16x16x32_bf16(vf, pf, oo[f], 0, 0, 0);
      }
    }
  }

  const float inv = 1.f / l_;
#pragma unroll
  for (int f = 0; f < 4; ++f) {
    ushort4 pk;
    pk.x = f2bf(oo[f][0] * inv); pk.y = f2bf(oo[f][1] * inv);
    pk.z = f2bf(oo[f][2] * inv); pk.w = f2bf(oo[f][3] * inv);
    int d0 = f * 16 + ((lane >> 4) << 2);
    *(ushort4*)(ob + (g << 9) + h * 64 + d0) = pk;
  }
}

// ---------------------------------------------------------------------------
extern "C" void kernel_launch(void* const* d_in, const int* in_sizes, int n_in,
                              void* d_out, int out_size, void* d_ws, size_t ws_size,
                              hipStream_t stream)
{
  const float* x     = (const float*)d_in[0];
  const float* dx    = (const float*)d_in[1];   // [64,8,1,512] rows t*8+b
  const float* qkv_w = (const float*)d_in[3];
  const float* qkv_b = (const float*)d_in[4];
  const float* out_w = (const float*)d_in[5];
  const float* out_b = (const float*)d_in[6];
  const float* w1    = (const float*)d_in[7];
  const float* b1    = (const float*)d_in[8];
  const float* w2    = (const float*)d_in[9];
  const float* b2    = (const float*)d_in[10];
  const float* ln1w  = (const float*)d_in[11];
  const float* ln1b  = (const float*)d_in[12];
  const float* ln2w  = (const float*)d_in[13];
  const float* ln2b  = (const float*)d_in[14];
  float* out = (float*)d_out;

  // M = 8704 rows: 8192 prefill tokens + 512 decode tokens (row 8192 + t*8+b)
  float* ws = (float*)d_ws;
  size_t o = 0;
  unsigned short* x_bf    = (unsigned short*)(ws + o); o += (size_t)8704 * 256;
  unsigned short* qkvw_bf = (unsigned short*)(ws + o); o += 1536 * 256;
  unsigned short* outw_bf = (unsigned short*)(ws + o); o += 512 * 256;
  unsigned short* w1_bf   = (unsigned short*)(ws + o); o += 2048 * 256;
  unsigned short* w2_bf   = (unsigned short*)(ws + o); o += (size_t)512 * 1024;
  unsigned short* qb_bf   = (unsigned short*)(ws + o); o += (size_t)8704 * 256;
  unsigned short* kcb     = (unsigned short*)(ws + o); o += (size_t)8 * CAP_ * 256;
  unsigned short* vtb     = (unsigned short*)(ws + o); o += (size_t)8 * 512 * CAP_ / 2;
  unsigned short* attn_bf = (unsigned short*)(ws + o); o += (size_t)8704 * 256;
  unsigned short* h1_bf   = (unsigned short*)(ws + o); o += (size_t)8704 * 256;
  unsigned short* hid_bf  = (unsigned short*)(ws + o); o += (size_t)8704 * 1024;

  // ---- all conversions in one launch ----
  cvt_all<<<dim3(7424), 256, 0, stream>>>(x, dx, qkv_w, out_w, w1, w2,
      x_bf, qkvw_bf, outw_bf, w1_bf, w2_bf);

  // ---- QKV (prefill + all decode steps), outputs bf16 q / K-cache / V^T ----
  mfma_gemm<<<dim3(68, 12), 256, 0, stream>>>(x_bf, qkvw_bf, qkv_b,
      qb_bf, kcb, vtb, 8704, 1536, 512, 1, 0);
  // ---- attention: prefill tiles 0..15 + decode tile 16 ----
  attn_mfma<<<dim3(17, 64), 256, 0, stream>>>(qb_bf, kcb, vtb, attn_bf);
  // ---- out-proj + residual(x_bf) + LN1, fused -> h1_bf ----
  gemm_fullrow_ln<<<dim3(272), 512, 0, stream>>>(attn_bf, outw_bf, out_b,
      x_bf, ln1w, ln1b, h1_bf, nullptr, 512, 0);
  // ---- MLP1 (relu, bf16 out) ----
  mfma_gemm<<<dim3(68, 16), 256, 0, stream>>>(h1_bf, w1_bf, b1,
      hid_bf, nullptr, nullptr, 8704, 2048, 512, 2, 1);
  // ---- MLP2 + residual(h1_bf) + LN2, fused -> routed fp32 d_out ----
  gemm_fullrow_ln<<<dim3(272), 512, 0, stream>>>(hid_bf, w2_bf, b2,
      h1_bf, ln2w, ln2b, nullptr, out, 2048, 1);
}

// Round 11
// 290.159 us; speedup vs baseline: 1.1919x; 1.1919x over previous
//
#include <hip/hip_runtime.h>
#include <cstdint>

#define CAP_ 1088
#define EPS_ 1e-5f

using bf8   = __attribute__((ext_vector_type(8))) short;
using f32x4 = __attribute__((ext_vector_type(4))) float;

__device__ __forceinline__ unsigned short f2bf(float f) {
  unsigned u = __float_as_uint(f);
  u += 0x7fffu + ((u >> 16) & 1);
  return (unsigned short)(u >> 16);
}
__device__ __forceinline__ float bf2f(unsigned short v) {
  return __uint_as_float((unsigned)v << 16);
}

typedef const __attribute__((address_space(1))) void* gp1;
typedef __attribute__((address_space(3))) void* lp3;
__device__ __forceinline__ void async16(const void* g, void* l) {
  __builtin_amdgcn_global_load_lds((gp1)g, (lp3)l, 16, 0, 0);
}

// ---------------------------------------------------------------------------
// All fp32->bf16 conversions in ONE kernel (segmented by blockIdx).
// ---------------------------------------------------------------------------
__global__ __launch_bounds__(256) void cvt_all(
    const float* __restrict__ x, const float* __restrict__ dx,
    const float* __restrict__ qkvw, const float* __restrict__ outw,
    const float* __restrict__ w1, const float* __restrict__ w2,
    unsigned short* __restrict__ x_bf, unsigned short* __restrict__ qkvw_bf,
    unsigned short* __restrict__ outw_bf, unsigned short* __restrict__ w1_bf,
    unsigned short* __restrict__ w2_bf)
{
  const int bid = blockIdx.x;
  const float* src; unsigned short* dst; int c;
  if      (bid < 4096) { src = x;    dst = x_bf;                      c = bid;        }
  else if (bid < 4352) { src = dx;   dst = x_bf + (size_t)8192 * 512; c = bid - 4096; }
  else if (bid < 5120) { src = qkvw; dst = qkvw_bf;                   c = bid - 4352; }
  else if (bid < 5376) { src = outw; dst = outw_bf;                   c = bid - 5120; }
  else if (bid < 6400) { src = w1;   dst = w1_bf;                     c = bid - 5376; }
  else                 { src = w2;   dst = w2_bf;                     c = bid - 6400; }
  const int i = c * 256 + threadIdx.x;
  float4 v = ((const float4*)src)[i];
  ushort4 o;
  o.x = f2bf(v.x); o.y = f2bf(v.y); o.z = f2bf(v.z); o.w = f2bf(v.w);
  ((ushort4*)dst)[i] = o;
}

// ---------------------------------------------------------------------------
// bf16 MFMA GEMM NT (128x128 tile, BK=64, 4 waves): QKV (mode 1) and
// MLP1 (mode 2, bf16 C + relu). Unchanged.
// ---------------------------------------------------------------------------
__global__ __launch_bounds__(256) void mfma_gemm(
    const unsigned short* __restrict__ A, const unsigned short* __restrict__ Bw,
    const float* __restrict__ bias,
    unsigned short* __restrict__ Cb,
    unsigned short* __restrict__ kb, unsigned short* __restrict__ vt,
    int M, int N, int K, int mode, int relu)
{
  __shared__ unsigned short Als[128 * 64];
  __shared__ unsigned short Bls[128 * 64];
  const int tid  = threadIdx.x;
  const int lane = tid & 63, w = tid >> 6;
  const int bm = blockIdx.x * 128, bn = blockIdx.y * 128;
  const int wm = (w >> 1) * 64, wn = (w & 1) * 64;

  f32x4 acc[4][4] = {};

  const int so = tid * 16;
  for (int k0 = 0; k0 < K; k0 += 64) {
#pragma unroll
    for (int it = 0; it < 4; ++it) {
      int o   = it * 4096 + so;
      int row = o >> 7;
      int ch  = (o >> 4) & 7;
      int sch = ch ^ (row & 7);
      async16(A  + (size_t)(bm + row) * K + k0 + sch * 8, (char*)Als + o);
      async16(Bw + (size_t)(bn + row) * K + k0 + sch * 8, (char*)Bls + o);
    }
    __syncthreads();
#pragma unroll
    for (int ks = 0; ks < 2; ++ks) {
      bf8 af[4], bfr[4];
#pragma unroll
      for (int m = 0; m < 4; ++m) {
        int row = wm + m * 16 + (lane & 15);
        int ch  = ks * 4 + (lane >> 4);
        af[m] = *(const bf8*)((const char*)Als + row * 128 + ((ch ^ (row & 7)) * 16));
      }
#pragma unroll
      for (int n = 0; n < 4; ++n) {
        int row = wn + n * 16 + (lane & 15);
        int ch  = ks * 4 + (lane >> 4);
        bfr[n] = *(const bf8*)((const char*)Bls + row * 128 + ((ch ^ (row & 7)) * 16));
      }
#pragma unroll
      for (int m = 0; m < 4; ++m)
#pragma unroll
        for (int n = 0; n < 4; ++n)
          acc[m][n] = __builtin_amdgcn_mfma_f32_16x16x32_bf16(af[m], bfr[n], acc[m][n], 0, 0, 0);
    }
    __syncthreads();
  }

#pragma unroll
  for (int m = 0; m < 4; ++m) {
#pragma unroll
    for (int n = 0; n < 4; ++n) {
      int col  = bn + wn + n * 16 + (lane & 15);
      int row0 = bm + wm + m * 16 + ((lane >> 4) << 2);
      float bcol = bias[col];
      if (mode == 1) {
        if (col < 512) {
#pragma unroll
          for (int r = 0; r < 4; ++r)
            Cb[((size_t)(row0 + r) << 9) + col] = f2bf((acc[m][n][r] + bcol) * 0.125f);
        } else if (col < 1024) {
#pragma unroll
          for (int r = 0; r < 4; ++r) {
            int row = row0 + r; int bb, pos;
            if (row < 8192) { bb = row >> 10; pos = row & 1023; }
            else { int r2 = row - 8192; bb = r2 & 7; pos = 1024 + (r2 >> 3); }
            kb[(((size_t)(bb * CAP_ + pos)) << 9) + (col - 512)] = f2bf(acc[m][n][r] + bcol);
          }
        } else {
          int c = col - 1024; int hh = c >> 6, d = c & 63;
          if (row0 < 8192) {
            int bb = row0 >> 10, pos = row0 & 1023;
            ushort4 pk;
            pk.x = f2bf(acc[m][n][0] + bcol); pk.y = f2bf(acc[m][n][1] + bcol);
            pk.z = f2bf(acc[m][n][2] + bcol); pk.w = f2bf(acc[m][n][3] + bcol);
            *(ushort4*)(vt + ((size_t)((bb * 8 + hh) * 64 + d)) * CAP_ + pos) = pk;
          } else {
#pragma unroll
            for (int r = 0; r < 4; ++r) {
              int r2 = row0 + r - 8192; int bb = r2 & 7, pos = 1024 + (r2 >> 3);
              vt[((size_t)((bb * 8 + hh) * 64 + d)) * CAP_ + pos] = f2bf(acc[m][n][r] + bcol);
            }
          }
        }
      } else {
#pragma unroll
        for (int r = 0; r < 4; ++r) {
          float v = acc[m][n][r] + bcol;
          if (relu) v = fmaxf(v, 0.f);
          Cb[(size_t)(row0 + r) * N + col] = f2bf(v);
        }
      }
    }
  }
}

// ---------------------------------------------------------------------------
// Full-row fused GEMM + residual + LayerNorm for N=512 outputs.
// EXACT round-6 version (proven 70.9 us): 256 thr = 4 waves, 32 rows x 512
// cols, BK=64 single 64KB swizzled buffer staged block-wide (16 async16 per
// thread = high MLP), 2 barriers per tile. A frags next-iter prefetched.
// mode 0: bf16 outb[row*512+col]; mode 1: fp32 outf routed (b,s).
// ---------------------------------------------------------------------------
__global__ __launch_bounds__(256) void gemm_fullrow_ln(
    const unsigned short* __restrict__ A,     // [8704][K]
    const unsigned short* __restrict__ Bw,    // [512][K]
    const float* __restrict__ bias,           // [512]
    const unsigned short* __restrict__ resb,  // [8704][512] bf16
    const float* __restrict__ lnw, const float* __restrict__ lnb,
    unsigned short* __restrict__ outb, float* __restrict__ outf,
    int K, int mode)
{
  __shared__ unsigned short Bls[512 * 64];    // 64 KB, reused for LN reduce
  const int tid = threadIdx.x, lane = tid & 63, w = tid >> 6;
  const int l4 = lane >> 4, l15 = lane & 15;
  const int bm = blockIdx.x * 32;

  f32x4 acc[2][8] = {};
  bf8 a_cur[2][2], a_nxt[2][2];

#pragma unroll
  for (int ks = 0; ks < 2; ++ks)
#pragma unroll
    for (int mf = 0; mf < 2; ++mf)
      a_cur[ks][mf] = *(const bf8*)(A + (size_t)(bm + mf * 16 + l15) * K + (ks * 4 + l4) * 8);

  for (int k0 = 0; k0 < K; k0 += 64) {
#pragma unroll
    for (int it = 0; it < 16; ++it) {
      int o   = it * 4096 + tid * 16;
      int row = o >> 7;                       // 0..511 (B row = out col)
      int sch = ((o >> 4) & 7) ^ (row & 7);
      async16(Bw + (size_t)row * K + k0 + sch * 8, (char*)Bls + o);
    }
    if (k0 + 64 < K) {
#pragma unroll
      for (int ks = 0; ks < 2; ++ks)
#pragma unroll
        for (int mf = 0; mf < 2; ++mf)
          a_nxt[ks][mf] = *(const bf8*)(A + (size_t)(bm + mf * 16 + l15) * K +
                                        k0 + 64 + (ks * 4 + l4) * 8);
    }
    __syncthreads();                          // B staged (vmcnt drained)
#pragma unroll
    for (int ks = 0; ks < 2; ++ks) {
      int cb = ks * 4 + l4;
#pragma unroll
      for (int nf = 0; nf < 8; ++nf) {
        int row = w * 128 + nf * 16 + l15;
        bf8 bfv = *(const bf8*)((const char*)Bls + row * 128 + ((cb ^ (row & 7)) << 4));
#pragma unroll
        for (int mf = 0; mf < 2; ++mf)
          acc[mf][nf] = __builtin_amdgcn_mfma_f32_16x16x32_bf16(a_cur[ks][mf], bfv, acc[mf][nf], 0, 0, 0);
      }
    }
#pragma unroll
    for (int ks = 0; ks < 2; ++ks)
#pragma unroll
      for (int mf = 0; mf < 2; ++mf)
        a_cur[ks][mf] = a_nxt[ks][mf];
    __syncthreads();                          // B reads done before restage
  }

  // ---- epilogue: bias + residual, then LN over the full 512-col row ----
  float bc[8], lw[8], lb[8];
#pragma unroll
  for (int nf = 0; nf < 8; ++nf) {
    int col = w * 128 + nf * 16 + l15;
    bc[nf] = bias[col]; lw[nf] = lnw[col]; lb[nf] = lnb[col];
  }
#pragma unroll
  for (int nf = 0; nf < 8; ++nf) {
    int col = w * 128 + nf * 16 + l15;
#pragma unroll
    for (int mf = 0; mf < 2; ++mf)
#pragma unroll
      for (int r = 0; r < 4; ++r) {
        int rowg = bm + mf * 16 + l4 * 4 + r;
        acc[mf][nf][r] += bc[nf] + bf2f(resb[(size_t)rowg * 512 + col]);
      }
  }

  float* red = (float*)Bls;                   // [32 rows][4 waves][2]
#pragma unroll
  for (int mf = 0; mf < 2; ++mf)
#pragma unroll
    for (int r = 0; r < 4; ++r) {
      float s = 0.f, q = 0.f;
#pragma unroll
      for (int nf = 0; nf < 8; ++nf) { float v = acc[mf][nf][r]; s += v; q += v * v; }
#pragma unroll
      for (int off = 1; off < 16; off <<= 1) {
        s += __shfl_xor(s, off, 64); q += __shfl_xor(q, off, 64);
      }
      if (l15 == 0) {
        int rl = mf * 16 + l4 * 4 + r;
        red[rl * 8 + w * 2]     = s;
        red[rl * 8 + w * 2 + 1] = q;
      }
    }
  __syncthreads();

#pragma unroll
  for (int mf = 0; mf < 2; ++mf)
#pragma unroll
    for (int r = 0; r < 4; ++r) {
      int rl = mf * 16 + l4 * 4 + r;
      float S = red[rl * 8 + 0] + red[rl * 8 + 2] + red[rl * 8 + 4] + red[rl * 8 + 6];
      float Q = red[rl * 8 + 1] + red[rl * 8 + 3] + red[rl * 8 + 5] + red[rl * 8 + 7];
      float mu  = S * (1.f / 512.f);
      float var = Q * (1.f / 512.f) - mu * mu;
      float inv = rsqrtf(var + EPS_);
      int rowg = bm + rl;
      if (mode == 0) {
#pragma unroll
        for (int nf = 0; nf < 8; ++nf) {
          int col = w * 128 + nf * 16 + l15;
          float y = (acc[mf][nf][r] - mu) * inv * lw[nf] + lb[nf];
          outb[(size_t)rowg * 512 + col] = f2bf(y);
        }
      } else {
        int b, s2;
        if (rowg < 8192) { b = rowg >> 10; s2 = rowg & 1023; }
        else { int r2 = rowg - 8192; b = r2 & 7; s2 = 1024 + (r2 >> 3); }
        size_t ob = ((size_t)(b * CAP_ + s2)) << 9;
#pragma unroll
        for (int nf = 0; nf < 8; ++nf) {
          int col = w * 128 + nf * 16 + l15;
          outf[ob + col] = (acc[mf][nf][r] - mu) * inv * lw[nf] + lb[nf];
        }
      }
    }
}

// ---------------------------------------------------------------------------
// MFMA attention. grid (17,64). Round-5 structure + T5 setprio around the
// MFMA clusters (attn blocks are independent & phase-diverse -> m191 +4-7%).
// ---------------------------------------------------------------------------
__global__ __launch_bounds__(256) void attn_mfma(
    const unsigned short* __restrict__ qb,   // [8704][512], pre-scaled 1/8
    const unsigned short* __restrict__ kcb,  // [8][1088][512]
    const unsigned short* __restrict__ vtb,  // [8][8][64][1088]
    unsigned short* __restrict__ ob)         // [8704][512]
{
  __shared__ unsigned short Kls[4096];
  __shared__ unsigned short Vls[4096];
  __shared__ unsigned short Pls[4096];
  const int st = blockIdx.x, bh = blockIdx.y;
  const int b = bh >> 3, h = bh & 7;
  const bool dec = (st == 16);
  const int tid = threadIdx.x, lane = tid & 63, w = tid >> 6;
  const int wq = w * 16;
  const int nT = dec ? 17 : st + 1;
  const int qi = wq + (lane & 15);
  const size_t g = dec ? (size_t)(8192 + qi * 8 + b)
                       : (size_t)((b << 10) + st * 64 + qi);

  const bf8 qf0 = *(const bf8*)(qb + (g << 9) + h * 64 +      ((lane >> 4) << 3));
  const bf8 qf1 = *(const bf8*)(qb + (g << 9) + h * 64 + 32 + ((lane >> 4) << 3));

  f32x4 oo[4] = {};
  float m_ = -1e30f, l_ = 0.f;

  const size_t kbase = (((size_t)b * CAP_) << 9) + h * 64;
  const size_t vbase = (size_t)((b * 8 + h) * 64) * CAP_;

  for (int t = 0; t < nT; ++t) {
    const int t0 = t * 64;
    __syncthreads();
#pragma unroll
    for (int it = 0; it < 2; ++it) {
      int o   = it * 4096 + tid * 16;
      int row = o >> 7;
      int sch = ((o >> 4) & 7) ^ (row & 7);
      async16(kcb + kbase + (((size_t)(t0 + row)) << 9) + sch * 8, (char*)Kls + o);
      async16(vtb + vbase + (size_t)row * CAP_ + t0 + sch * 8,     (char*)Vls + o);
    }
    __syncthreads();

    f32x4 sfr[4] = {};
    __builtin_amdgcn_s_setprio(1);
#pragma unroll
    for (int ks = 0; ks < 2; ++ks) {
      int cb = ks * 4 + (lane >> 4);
      bf8 qv = ks ? qf1 : qf0;
#pragma unroll
      for (int f = 0; f < 4; ++f) {
        int row = f * 16 + (lane & 15);
        bf8 kf = *(const bf8*)((const char*)Kls + row * 128 + ((cb ^ (row & 7)) << 4));
        sfr[f] = __builtin_amdgcn_mfma_f32_16x16x32_bf16(kf, qv, sfr[f], 0, 0, 0);
      }
    }
    __builtin_amdgcn_s_setprio(0);
    if (t == nT - 1) {
#pragma unroll
      for (int f = 0; f < 4; ++f)
#pragma unroll
        for (int r = 0; r < 4; ++r) {
          int tr = f * 16 + ((lane >> 4) << 2) + r;
          if (tr > qi) sfr[f][r] = -1e30f;
        }
    }

    float pmax = -1e30f;
#pragma unroll
    for (int f = 0; f < 4; ++f)
#pragma unroll
      for (int r = 0; r < 4; ++r) pmax = fmaxf(pmax, sfr[f][r]);
    pmax = fmaxf(pmax, __shfl_xor(pmax, 16, 64));
    pmax = fmaxf(pmax, __shfl_xor(pmax, 32, 64));
    float mn  = fmaxf(m_, pmax);
    float fsc = __expf(m_ - mn);
    float rs = 0.f;
#pragma unroll
    for (int f = 0; f < 4; ++f)
#pragma unroll
      for (int r = 0; r < 4; ++r) {
        float e = __expf(sfr[f][r] - mn);
        sfr[f][r] = e; rs += e;
      }
    rs += __shfl_xor(rs, 16, 64);
    rs += __shfl_xor(rs, 32, 64);
    l_ = l_ * fsc + rs; m_ = mn;
#pragma unroll
    for (int f = 0; f < 4; ++f) oo[f] *= fsc;

#pragma unroll
    for (int f = 0; f < 4; ++f) {
      ushort4 pk;
      pk.x = f2bf(sfr[f][0]); pk.y = f2bf(sfr[f][1]);
      pk.z = f2bf(sfr[f][2]); pk.w = f2bf(sfr[f][3]);
      int tb   = f * 32 + ((lane >> 4) << 3);
      int addr = qi * 128 + ((((tb >> 4)) ^ (qi & 7)) << 4) + (tb & 15);
      *(ushort4*)((char*)Pls + addr) = pk;
    }
    __syncthreads();

    __builtin_amdgcn_s_setprio(1);
#pragma unroll
    for (int ks = 0; ks < 2; ++ks) {
      int cb = ks * 4 + (lane >> 4);
      bf8 pf = *(const bf8*)((const char*)Pls + qi * 128 + ((cb ^ (qi & 7)) << 4));
#pragma unroll
      for (int f = 0; f < 4; ++f) {
        int row = f * 16 + (lane & 15);
        bf8 vf = *(const bf8*)((const char*)Vls + row * 128 + ((cb ^ (row & 7)) << 4));
        oo[f] = __builtin_amdgcn_mfma_f32_16x16x32_bf16(vf, pf, oo[f], 0, 0, 0);
      }
    }
    __builtin_amdgcn_s_setprio(0);
  }

  const float inv = 1.f / l_;
#pragma unroll
  for (int f = 0; f < 4; ++f) {
    ushort4 pk;
    pk.x = f2bf(oo[f][0] * inv); pk.y = f2bf(oo[f][1] * inv);
    pk.z = f2bf(oo[f][2] * inv); pk.w = f2bf(oo[f][3] * inv);
    int d0 = f * 16 + ((lane >> 4) << 2);
    *(ushort4*)(ob + (g << 9) + h * 64 + d0) = pk;
  }
}

// ---------------------------------------------------------------------------
extern "C" void kernel_launch(void* const* d_in, const int* in_sizes, int n_in,
                              void* d_out, int out_size, void* d_ws, size_t ws_size,
                              hipStream_t stream)
{
  const float* x     = (const float*)d_in[0];
  const float* dx    = (const float*)d_in[1];   // [64,8,1,512] rows t*8+b
  const float* qkv_w = (const float*)d_in[3];
  const float* qkv_b = (const float*)d_in[4];
  const float* out_w = (const float*)d_in[5];
  const float* out_b = (const float*)d_in[6];
  const float* w1    = (const float*)d_in[7];
  const float* b1    = (const float*)d_in[8];
  const float* w2    = (const float*)d_in[9];
  const float* b2    = (const float*)d_in[10];
  const float* ln1w  = (const float*)d_in[11];
  const float* ln1b  = (const float*)d_in[12];
  const float* ln2w  = (const float*)d_in[13];
  const float* ln2b  = (const float*)d_in[14];
  float* out = (float*)d_out;

  // M = 8704 rows: 8192 prefill tokens + 512 decode tokens (row 8192 + t*8+b)
  float* ws = (float*)d_ws;
  size_t o = 0;
  unsigned short* x_bf    = (unsigned short*)(ws + o); o += (size_t)8704 * 256;
  unsigned short* qkvw_bf = (unsigned short*)(ws + o); o += 1536 * 256;
  unsigned short* outw_bf = (unsigned short*)(ws + o); o += 512 * 256;
  unsigned short* w1_bf   = (unsigned short*)(ws + o); o += 2048 * 256;
  unsigned short* w2_bf   = (unsigned short*)(ws + o); o += (size_t)512 * 1024;
  unsigned short* qb_bf   = (unsigned short*)(ws + o); o += (size_t)8704 * 256;
  unsigned short* kcb     = (unsigned short*)(ws + o); o += (size_t)8 * CAP_ * 256;
  unsigned short* vtb     = (unsigned short*)(ws + o); o += (size_t)8 * 512 * CAP_ / 2;
  unsigned short* attn_bf = (unsigned short*)(ws + o); o += (size_t)8704 * 256;
  unsigned short* h1_bf   = (unsigned short*)(ws + o); o += (size_t)8704 * 256;
  unsigned short* hid_bf  = (unsigned short*)(ws + o); o += (size_t)8704 * 1024;

  // ---- all conversions in one launch ----
  cvt_all<<<dim3(7424), 256, 0, stream>>>(x, dx, qkv_w, out_w, w1, w2,
      x_bf, qkvw_bf, outw_bf, w1_bf, w2_bf);

  // ---- QKV (prefill + all decode steps), outputs bf16 q / K-cache / V^T ----
  mfma_gemm<<<dim3(68, 12), 256, 0, stream>>>(x_bf, qkvw_bf, qkv_b,
      qb_bf, kcb, vtb, 8704, 1536, 512, 1, 0);
  // ---- attention: prefill tiles 0..15 + decode tile 16 ----
  attn_mfma<<<dim3(17, 64), 256, 0, stream>>>(qb_bf, kcb, vtb, attn_bf);
  // ---- out-proj + residual(x_bf) + LN1, fused -> h1_bf ----
  gemm_fullrow_ln<<<dim3(272), 256, 0, stream>>>(attn_bf, outw_bf, out_b,
      x_bf, ln1w, ln1b, h1_bf, nullptr, 512, 0);
  // ---- MLP1 (relu, bf16 out) ----
  mfma_gemm<<<dim3(68, 16), 256, 0, stream>>>(h1_bf, w1_bf, b1,
      hid_bf, nullptr, nullptr, 8704, 2048, 512, 2, 1);
  // ---- MLP2 + residual(h1_bf) + LN2, fused -> routed fp32 d_out ----
  gemm_fullrow_ln<<<dim3(272), 256, 0, stream>>>(hid_bf, w2_bf, b2,
      h1_bf, ln2w, ln2b, nullptr, out, 2048, 1);
}